// Round 1
// baseline (1513.031 us; speedup 1.0000x reference)
//
#include <hip/hip_runtime.h>
#include <math.h>

typedef __bf16 bf16;
typedef __bf16 bf16x8 __attribute__((ext_vector_type(8)));
typedef float f32x4 __attribute__((ext_vector_type(4)));

#define MFMA_B16(a,b,c) __builtin_amdgcn_mfma_f32_16x16x32_bf16((a),(b),(c),0,0,0)

constexpr int TMAXc = 30;
constexpr int Bc = 128, Pc = 196, Fc = 2048, Ec = 512, Hc = 1024, Vc = 10000;
constexpr int G4c = 4 * Hc;          // 4096
constexpr int NSTEP = TMAXc + 1;     // 31
constexpr int MALLc = NSTEP * Bc;    // 3968
constexpr int MOUTc = TMAXc * Bc;    // 3840

__device__ __forceinline__ float sigm(float x){ return 1.0f/(1.0f+expf(-x)); }

__device__ __forceinline__ void gll16(const void* g, void* l){
  __builtin_amdgcn_global_load_lds((const __attribute__((address_space(1))) void*)g,
                                   (__attribute__((address_space(3))) void*)l, 16, 0, 0);
}

// ---------------- prep kernels ----------------

__global__ void mean_kernel(const float* __restrict__ enc, bf16* __restrict__ feat){
  int idx = blockIdx.x*256 + threadIdx.x;
  if (idx >= Bc*Fc) return;
  int b = idx >> 11, f = idx & (Fc-1);
  const float* p = enc + (size_t)b*Pc*Fc + f;
  float s = 0.f;
  for (int q = 0; q < Pc; ++q) s += p[(size_t)q*Fc];
  feat[idx] = (bf16)(s * (1.0f/(float)Pc));
}

__global__ void conv_kernel(const float* __restrict__ src, bf16* __restrict__ dst, int n){
  int i = blockIdx.x*256 + threadIdx.x;
  if (i < n) dst[i] = (bf16)src[i];
}

// W_ih (4096,512) -> permuted rows: row' = j*4+g  <-  row g*1024+j ; plain bf16
__global__ void permconv_ih(const float* __restrict__ W, bf16* __restrict__ Wp){
  int i = blockIdx.x*256 + threadIdx.x;
  if (i >= G4c*Ec) return;
  int rp = i >> 9, k = i & 511;
  int g = rp & 3, j = rp >> 2;
  Wp[i] = (bf16)W[(size_t)(g*Hc + j)*Ec + k];
}

// W_hh (4096,1024) -> permuted + split hi/lo
__global__ void permsplit_hh(const float* __restrict__ W, bf16* __restrict__ Whi, bf16* __restrict__ Wlo){
  int i = blockIdx.x*256 + threadIdx.x;
  if (i >= G4c*Hc) return;
  int rp = i >> 10, k = i & 1023;
  int g = rp & 3, j = rp >> 2;
  float v = W[(size_t)(g*Hc + j)*Hc + k];
  bf16 h = (bf16)v;
  Whi[i] = h; Wlo[i] = (bf16)(v - (float)h);
}

__global__ void split_kernel(const float* __restrict__ W, bf16* __restrict__ Whi, bf16* __restrict__ Wlo, int n){
  int i = blockIdx.x*256 + threadIdx.x;
  if (i >= n) return;
  float v = W[i]; bf16 h = (bf16)v;
  Whi[i] = h; Wlo[i] = (bf16)(v - (float)h);
}

__global__ void bcomb_kernel(const float* __restrict__ bih, const float* __restrict__ bhh, float* __restrict__ bc){
  int i = blockIdx.x*256 + threadIdx.x;
  if (i >= G4c) return;
  int g = i & 3, j = i >> 2;
  bc[i] = bih[g*Hc + j] + bhh[g*Hc + j];
}

// embedding gather into X_all rows 128..3967 (row = s*128+b holds x_s = emb_{s-1})
__global__ void gather_kernel(const float* __restrict__ emb, const int* __restrict__ gt, bf16* __restrict__ X){
  int idx = blockIdx.x*256 + threadIdx.x;
  if (idx >= MOUTc*(Ec/4)) return;
  int r = idx >> 7, ei = (idx & 127) * 4;
  int s = (r >> 7) + 1, b = r & 127;
  int tok = gt[b*(TMAXc+1) + (s-1)];
  const float* src = emb + (size_t)tok*Ec + ei;
  bf16* dst = X + (size_t)(s*Bc + b)*Ec + ei;
  dst[0]=(bf16)src[0]; dst[1]=(bf16)src[1]; dst[2]=(bf16)src[2]; dst[3]=(bf16)src[3];
}

// ---------------- generic MFMA GEMM (m97 structure, 128x128 tile, BK=32) ----------------
// C[m,n] = sum_k A[m,k]*B[n,k]  (B is N x K row-major). EPI: 0=x0(sig+BN), 1=Xg(bias), 2=FC(bias+mask)
template<int EPI, bool SPLIT>
__global__ __launch_bounds__(256, 2) void gemm_kernel(
  const bf16* __restrict__ Ahi, const bf16* __restrict__ Alo,
  const bf16* __restrict__ Bhi, const bf16* __restrict__ Blo,
  int M, int N, int K, int ntiles,
  const float* __restrict__ p0, const float* __restrict__ p1, const float* __restrict__ p2,
  bf16* __restrict__ outb, float* __restrict__ outf, const int* __restrict__ lens)
{
  constexpr int BK = 32;
  __shared__ alignas(16) bf16 sAh[128*BK], sBh[128*BK];
  __shared__ alignas(16) bf16 sAl[SPLIT ? 128*BK : 8], sBl[SPLIT ? 128*BK : 8];

  int tid = threadIdx.x;
  int lane = tid & 63, w = tid >> 6, wr = w >> 1, wc = w & 1;
  int bid = blockIdx.x;
  int mt = bid / ntiles, nt = bid - mt*ntiles;
  int m0 = mt*128, n0 = nt*128;

  f32x4 acc[4][4] = {};

  for (int kt = 0; kt < K; kt += BK) {
    #pragma unroll
    for (int is = 0; is < 2; ++is) {
      int p = tid*16 + is*4096;          // byte offset in 8KB tile
      int r = p >> 6, c = (p & 63) >> 1; // row, elem-col
      int ldsoff = w*512 + is*2048;      // elems (wave-uniform base)
      gll16(Ahi + (size_t)(m0 + r)*K + kt + c, &sAh[ldsoff]);
      int rb = n0 + r; rb = rb < N ? rb : N - 1;
      gll16(Bhi + (size_t)rb*K + kt + c, &sBh[ldsoff]);
      if constexpr (SPLIT) {
        gll16(Alo + (size_t)(m0 + r)*K + kt + c, &sAl[ldsoff]);
        gll16(Blo + (size_t)rb*K + kt + c, &sBl[ldsoff]);
      }
    }
    __syncthreads();

    int koff = (lane >> 4) * 8;
    bf16x8 ah[4], bh[4], al[SPLIT?4:1], bl[SPLIT?4:1];
    #pragma unroll
    for (int mi = 0; mi < 4; ++mi) {
      int rr = wr*64 + mi*16 + (lane & 15);
      ah[mi] = *(const bf16x8*)&sAh[rr*BK + koff];
      if constexpr (SPLIT) al[mi] = *(const bf16x8*)&sAl[rr*BK + koff];
    }
    #pragma unroll
    for (int ni = 0; ni < 4; ++ni) {
      int rr = wc*64 + ni*16 + (lane & 15);
      bh[ni] = *(const bf16x8*)&sBh[rr*BK + koff];
      if constexpr (SPLIT) bl[ni] = *(const bf16x8*)&sBl[rr*BK + koff];
    }
    #pragma unroll
    for (int mi = 0; mi < 4; ++mi)
      #pragma unroll
      for (int ni = 0; ni < 4; ++ni) {
        acc[mi][ni] = MFMA_B16(ah[mi], bh[ni], acc[mi][ni]);
        if constexpr (SPLIT) {
          acc[mi][ni] = MFMA_B16(ah[mi], bl[ni], acc[mi][ni]);
          acc[mi][ni] = MFMA_B16(al[mi], bh[ni], acc[mi][ni]);
        }
      }
    __syncthreads();
  }

  const float rbn = rsqrtf(1.0f + 1e-5f);
  #pragma unroll
  for (int mi = 0; mi < 4; ++mi) {
    #pragma unroll
    for (int ni = 0; ni < 4; ++ni) {
      int row = m0 + wr*64 + mi*16 + ((lane >> 4) << 2);
      int col = n0 + wc*64 + ni*16 + (lane & 15);
      #pragma unroll
      for (int j = 0; j < 4; ++j) {
        int rr = row + j;
        float v = acc[mi][ni][j];
        if constexpr (EPI == 0) {
          v = sigm(v + p0[col]);
          v = p1[col]*(v*rbn) + p2[col];
          outb[(size_t)rr*Ec + col] = (bf16)v;
        } else if constexpr (EPI == 1) {
          outb[(size_t)rr*G4c + col] = (bf16)(v + p0[col]);
        } else {
          if (col < N) {
            v += p0[col];
            int t = rr >> 7, b = rr & 127;
            float o = (t < (lens[b] - 1)) ? v : 0.0f;
            outf[(size_t)b*(TMAXc*Vc) + (size_t)t*Vc + col] = o;
          }
        }
      }
    }
  }
}

// ---------------- fused recurrent LSTM step ----------------
// gates(128 x 4096, permuted cols) = Xg[s] + h @ Whh_p^T (split-3), then LSTM epilogue.
// block bk owns permuted cols [bk*32, bk*32+32) = h cols [bk*8, bk*8+8)
__global__ __launch_bounds__(256, 2) void lstm_step(
  const bf16* __restrict__ hih, const bf16* __restrict__ hil,
  const bf16* __restrict__ Whi, const bf16* __restrict__ Wlo,
  const bf16* __restrict__ Xg, float* __restrict__ cst,
  bf16* __restrict__ hoh, bf16* __restrict__ hol,
  bf16* __restrict__ Hh, bf16* __restrict__ Hl, int s)
{
  constexpr int BK = 32;
  __shared__ alignas(16) bf16 sAh[128*BK], sAl[128*BK], sBh[32*BK], sBl[32*BK];
  int tid = threadIdx.x, lane = tid & 63, w = tid >> 6;
  int bk = blockIdx.x;
  int brow0 = bk * 32;

  f32x4 acc[2][2] = {};

  for (int kt = 0; kt < Hc; kt += BK) {
    #pragma unroll
    for (int is = 0; is < 2; ++is) {
      int p = tid*16 + is*4096;
      int r = p >> 6, c = (p & 63) >> 1;
      int ldsoff = w*512 + is*2048;
      gll16(hih + (size_t)r*Hc + kt + c, &sAh[ldsoff]);
      gll16(hil + (size_t)r*Hc + kt + c, &sAl[ldsoff]);
    }
    {
      int p = (tid & 127) * 16;
      int r = p >> 6, c = (p & 63) >> 1;
      const bf16* src = (w < 2) ? Whi : Wlo;
      bf16* dst = ((w < 2) ? sBh : sBl) + (w & 1) * 512;
      gll16(src + (size_t)(brow0 + r)*Hc + kt + c, dst);
    }
    __syncthreads();

    int koff = (lane >> 4) * 8;
    bf16x8 ah[2], al[2], bh[2], bl[2];
    #pragma unroll
    for (int mi = 0; mi < 2; ++mi) {
      int rr = w*32 + mi*16 + (lane & 15);
      ah[mi] = *(const bf16x8*)&sAh[rr*BK + koff];
      al[mi] = *(const bf16x8*)&sAl[rr*BK + koff];
    }
    #pragma unroll
    for (int ni = 0; ni < 2; ++ni) {
      int rr = ni*16 + (lane & 15);
      bh[ni] = *(const bf16x8*)&sBh[rr*BK + koff];
      bl[ni] = *(const bf16x8*)&sBl[rr*BK + koff];
    }
    #pragma unroll
    for (int mi = 0; mi < 2; ++mi)
      #pragma unroll
      for (int ni = 0; ni < 2; ++ni) {
        acc[mi][ni] = MFMA_B16(ah[mi], bh[ni], acc[mi][ni]);
        acc[mi][ni] = MFMA_B16(ah[mi], bl[ni], acc[mi][ni]);
        acc[mi][ni] = MFMA_B16(al[mi], bh[ni], acc[mi][ni]);
      }
    __syncthreads();
  }

  int e = lane & 3;
  #pragma unroll
  for (int mi = 0; mi < 2; ++mi) {
    #pragma unroll
    for (int ni = 0; ni < 2; ++ni) {
      int row = w*32 + mi*16 + ((lane >> 4) << 2);
      int pcol = brow0 + ni*16 + (lane & 15);
      int hcol = pcol >> 2;
      #pragma unroll
      for (int j = 0; j < 4; ++j) {
        int rr = row + j;
        float v = acc[mi][ni][j] + (float)Xg[(size_t)(s*Bc + rr)*G4c + pcol];
        float a = v;
        float b1 = __shfl_xor(v, 1);
        float c2 = __shfl_xor(v, 2);
        float d3 = __shfl_xor(v, 3);
        // gate q lives in the shuffle with mask (e^q): 0->a,1->b1,2->c2,3->d3
        int m;
        m = e;     float gI = (m==0)?a:(m==1)?b1:(m==2)?c2:d3;
        m = e ^ 1; float gF = (m==0)?a:(m==1)?b1:(m==2)?c2:d3;
        m = e ^ 2; float gG = (m==0)?a:(m==1)?b1:(m==2)?c2:d3;
        m = e ^ 3; float gO = (m==0)?a:(m==1)?b1:(m==2)?c2:d3;

        size_t oi = (size_t)rr*Hc + hcol;
        float co = cst[oi];
        float cn = sigm(gF)*co + sigm(gI)*tanhf(gG);
        float hn = sigm(gO)*tanhf(cn);
        bf16 hhi = (bf16)hn;
        bf16 hlo = (bf16)(hn - (float)hhi);
        if (e == 0) cst[oi] = cn;
        else if (e == 1) hoh[oi] = hhi;
        else if (e == 2) hol[oi] = hlo;
        else if (s > 0) {
          size_t ho = (size_t)((s-1)*Bc + rr)*Hc + hcol;
          Hh[ho] = hhi; Hl[ho] = hlo;
        }
      }
    }
  }
}

// ---------------- launch ----------------

extern "C" void kernel_launch(void* const* d_in, const int* in_sizes, int n_in,
                              void* d_out, int out_size, void* d_ws, size_t ws_size,
                              hipStream_t stream)
{
  const float* enc   = (const float*)d_in[0];
  const int*   gt    = (const int*)  d_in[1];
  const int*   lens  = (const int*)  d_in[2];
  const float* emb   = (const float*)d_in[3];
  const float* Winit = (const float*)d_in[4];
  const float* binit = (const float*)d_in[5];
  const float* gam   = (const float*)d_in[6];
  const float* bet   = (const float*)d_in[7];
  const float* Wih   = (const float*)d_in[8];
  const float* bih   = (const float*)d_in[9];
  const float* Whh   = (const float*)d_in[10];
  const float* bhh   = (const float*)d_in[11];
  const float* Wfc   = (const float*)d_in[12];
  const float* bfc   = (const float*)d_in[13];
  float* out = (float*)d_out;

  char* ws = (char*)d_ws;
  size_t off = 0;
  auto alloc = [&](size_t bytes) -> char* {
    char* p = ws + off;
    off += (bytes + 255) & ~(size_t)255;
    return p;
  };

  bf16* featB  = (bf16*)alloc((size_t)Bc*Fc*2);
  bf16* WinitB = (bf16*)alloc((size_t)Ec*Fc*2);
  bf16* WihpB  = (bf16*)alloc((size_t)G4c*Ec*2);
  bf16* WhhHi  = (bf16*)alloc((size_t)G4c*Hc*2);
  bf16* WhhLo  = (bf16*)alloc((size_t)G4c*Hc*2);
  bf16* WfcHi  = (bf16*)alloc((size_t)Vc*Hc*2);
  bf16* WfcLo  = (bf16*)alloc((size_t)Vc*Hc*2);
  float* bcomb = (float*)alloc((size_t)G4c*4);
  bf16* Xall   = (bf16*)alloc((size_t)MALLc*Ec*2);
  bf16* Xg     = (bf16*)alloc((size_t)MALLc*G4c*2);
  bf16* h0h    = (bf16*)alloc((size_t)Bc*Hc*2);
  bf16* h0l    = (bf16*)alloc((size_t)Bc*Hc*2);
  bf16* h1h    = (bf16*)alloc((size_t)Bc*Hc*2);
  bf16* h1l    = (bf16*)alloc((size_t)Bc*Hc*2);
  float* cst   = (float*)alloc((size_t)Bc*Hc*4);
  bf16* HallH  = (bf16*)alloc((size_t)MOUTc*Hc*2);
  bf16* HallL  = (bf16*)alloc((size_t)MOUTc*Hc*2);

  if (off > ws_size) return; // workspace too small -> fail loudly in validation

  // zero initial state
  hipMemsetAsync(h0h, 0, (size_t)Bc*Hc*2, stream);
  hipMemsetAsync(h0l, 0, (size_t)Bc*Hc*2, stream);
  hipMemsetAsync(cst, 0, (size_t)Bc*Hc*4, stream);

  // prep
  mean_kernel<<<(Bc*Fc + 255)/256, 256, 0, stream>>>(enc, featB);
  conv_kernel<<<((Ec*Fc) + 255)/256, 256, 0, stream>>>(Winit, WinitB, Ec*Fc);
  permconv_ih<<<((G4c*Ec) + 255)/256, 256, 0, stream>>>(Wih, WihpB);
  permsplit_hh<<<((G4c*Hc) + 255)/256, 256, 0, stream>>>(Whh, WhhHi, WhhLo);
  split_kernel<<<((Vc*Hc) + 255)/256, 256, 0, stream>>>(Wfc, WfcHi, WfcLo, Vc*Hc);
  bcomb_kernel<<<(G4c + 255)/256, 256, 0, stream>>>(bih, bhh, bcomb);
  gather_kernel<<<((MOUTc*(Ec/4)) + 255)/256, 256, 0, stream>>>(emb, gt, Xall);

  // GEMM A: x0 = sigmoid(feat @ Winit^T + b) * BN -> X_all rows 0..127
  gemm_kernel<0,false><<<1*4, 256, 0, stream>>>(
      featB, nullptr, WinitB, nullptr, Bc, Ec, Fc, 4,
      binit, gam, bet, Xall, nullptr, nullptr);

  // GEMM C: Xg = X_all @ Wihp^T + bcomb   (3968 x 4096, K=512)
  gemm_kernel<1,false><<<31*32, 256, 0, stream>>>(
      Xall, nullptr, WihpB, nullptr, MALLc, G4c, Ec, 32,
      bcomb, nullptr, nullptr, Xg, nullptr, nullptr);

  // recurrence: 31 fused steps
  bf16* hh[2] = {h0h, h1h};
  bf16* hl[2] = {h0l, h1l};
  for (int s = 0; s < NSTEP; ++s) {
    lstm_step<<<128, 256, 0, stream>>>(
        hh[s & 1], hl[s & 1], WhhHi, WhhLo, Xg, cst,
        hh[(s+1) & 1], hl[(s+1) & 1], HallH, HallL, s);
  }

  // GEMM E: preds = Hall @ Wfc^T + b_fc, masked -> out (split-3)
  gemm_kernel<2,true><<<30*79, 256, 0, stream>>>(
      HallH, HallL, WfcHi, WfcLo, MOUTc, Vc, Hc, 79,
      bfc, nullptr, nullptr, nullptr, out, lens);
}